// Round 7
// baseline (333.067 us; speedup 1.0000x reference)
//
#include <hip/hip_runtime.h>
#include <cfloat>
#include <climits>
#include <cstdint>

#define HH 1024
#define WW 2048
#define NPIX (HH * WW)
#define NWORD (NPIX / 64)
#define TPB 256
#define UNROLL 4
#define MAXI 200

#define BAND_LO 0.693130f
#define BAND_HI 0.693160f
#define LN2_CMP 0.6931472f

// ================= FAT (merged, compacted) layout =================
#define NBLK 512
#define WPB (NWORD / NBLK)           // 64 words per block, 16 per wave
#define F_CTL   ((size_t)0x0)        // ints: slots b*32 (b<512); FLG/NOW/CSUM
#define F_PK    ((size_t)0x20000)    // 2 par x 512 x 4 u64 {key,sa,sb,pad}
#define F_MASK  ((size_t)0x40000)    // 256 KB mask bitwords (wave-private plain)
#define F_WOFF  ((size_t)0x80000)    // 128 KB per-word compacted base (block-private)
#define F_UNCL  ((size_t)0xA0000)    // 256 KB compacted uncl bits (wave-private, loop map)
#define F_P1C   ((size_t)0xE0000)    // 256 KB compacted prop1 bits (wave-private, loop map)
#define CMAX    1220000
#define F_CEXY  ((size_t)0x120000)               // u64-atomic float2
#define F_CSM   (F_CEXY + (size_t)CMAX * 8 + 512)
#define F_CSV   (F_CSM + (size_t)CMAX * 4 + 512)
#define F_CSX   (F_CSV + (size_t)CMAX * 4 + 512)
#define F_CSY   (F_CSX + (size_t)CMAX * 4 + 512)
#define FAT_NEED ((size_t)0x2200000)
// F_CTL int indices
#define FC_FLG1 16384
#define FC_FLG2 16385
#define FC_NOW  16400   // 256 ints
#define FC_CSUM 16896   // 512 ints
#define FC_MEMSET_BYTES ((size_t)0x11000)   // covers 17408 ints

// ================= THIN fallback (round-6, proven) =================
#define T_MASK ((size_t)0x0)
#define T_UNCL ((size_t)0x40000)
#define T_P1   ((size_t)0x80000)
#define T_PV   ((size_t)0xC0000)
#define T_PSA  ((size_t)0xC2000)
#define T_PSB  ((size_t)0xC4000)
#define T_CTL  ((size_t)0xD0000)
#define T_NBLK 256
#define TC_REL  8192
#define TC_FLG1 8224
#define TC_FLG2 8225
#define TC_NOW  8256
#define TC_ZEND 16384

// ---- relaxed agent-scope atomics: bypass non-coherent per-XCD L2, land at the
// coherence point. No acq/rel fences -> no cache maintenance. Ordering comes
// from vmcnt(0) drains + the slot observation chain in the barrier.
__device__ __forceinline__ int al(const int* p) {
  return __hip_atomic_load((int*)p, __ATOMIC_RELAXED, __HIP_MEMORY_SCOPE_AGENT);
}
__device__ __forceinline__ void as_(int* p, int v) {
  __hip_atomic_store(p, v, __ATOMIC_RELAXED, __HIP_MEMORY_SCOPE_AGENT);
}
__device__ __forceinline__ uint64_t al64(const uint64_t* p) {
  return __hip_atomic_load((uint64_t*)p, __ATOMIC_RELAXED, __HIP_MEMORY_SCOPE_AGENT);
}
__device__ __forceinline__ void as64(uint64_t* p, uint64_t v) {
  __hip_atomic_store(p, v, __ATOMIC_RELAXED, __HIP_MEMORY_SCOPE_AGENT);
}

// seed_map = softmax(pred[5:7], axis=0)[1], op-for-op (max-subtract)
__device__ __forceinline__ float compute_sm(const float* __restrict__ pred, int i) {
  float a = pred[(size_t)5 * NPIX + i];
  float b = pred[(size_t)6 * NPIX + i];
  float m = fmaxf(a, b);
  float ea = expf(a - m);
  float eb = expf(b - m);
  return eb / (ea + eb);
}

__device__ __forceinline__ void compute_emb(const float* __restrict__ pred, int i,
                                            float& ex, float& ey) {
#pragma clang fp contract(off)
  int r = i >> 11;
  int c = i & (WW - 1);
  float xm = (float)c * (2.0f / 2047.0f);
  float ym = (float)r * (1.0f / 1023.0f);
  ex = tanhf(pred[i]) + xm;
  ey = tanhf(pred[(size_t)NPIX + i]) + ym;
}

// z with the reference's exact association; decision expf(-z)>0.5
__device__ __forceinline__ float prop_z(float ex, float ey, float cx, float cy,
                                        float sx, float sy) {
#pragma clang fp contract(off)
  float dx = ex - cx;
  float dy = ey - cy;
  float t0 = dx * dx; t0 = t0 * sx;
  float t1 = dy * dy; t1 = t1 * sy;
  return t0 + t1;
}

__device__ __forceinline__ bool prop_test(float ex, float ey, float cx, float cy,
                                          float sx, float sy) {
  float z = prop_z(ex, ey, cx, cy, sx, sy);
  float d = expf(-z);
  return d > 0.5f;
}

__device__ __forceinline__ uint64_t sh64(uint64_t v, int m) {
  return (uint64_t)__shfl_xor((unsigned long long)v, m, 64);
}

// block reduce: key = max (packed (val_bits<<32)|~idx), sa/sb u64 sums. Deterministic.
__device__ __forceinline__ void bred(uint64_t& key, uint64_t& sa, uint64_t& sb,
                                     uint64_t* lK, uint64_t* lA, uint64_t* lB) {
#pragma unroll
  for (int m = 1; m < 64; m <<= 1) {
    uint64_t k2 = sh64(key, m); if (k2 > key) key = k2;
    sa += sh64(sa, m);
    sb += sh64(sb, m);
  }
  int wid = threadIdx.x >> 6;
  if ((threadIdx.x & 63) == 0) { lK[wid] = key; lA[wid] = sa; lB[wid] = sb; }
  __syncthreads();
  key = lK[0]; sa = lA[0]; sb = lB[0];
#pragma unroll
  for (int w = 1; w < TPB / 64; w++) {
    uint64_t k2 = lK[w]; if (k2 > key) key = k2;
    sa += lA[w]; sb += lB[w];
  }
  __syncthreads();
}

// redundant global reduce over packed {key,sa,sb} partials
__device__ __forceinline__ void gred_pk(const uint64_t* PK, int par, int nblk,
                                        uint64_t& key, uint64_t& sa, uint64_t& sb,
                                        uint64_t* lK, uint64_t* lA, uint64_t* lB) {
  key = 0; sa = 0; sb = 0;
  for (int b = threadIdx.x; b < nblk; b += TPB) {
    const uint64_t* s = &PK[((size_t)par * NBLK + b) * 4];
    uint64_t k2 = al64(s + 0); if (k2 > key) key = k2;
    sa += al64(s + 1);
    sb += al64(s + 2);
  }
  bred(key, sa, sb, lK, lA, lB);
}

// decentralized slot barrier: arrive (own slot), every block's wave 0 polls all.
__device__ __forceinline__ void gbar_d(int* CTL, int nblk, int ph) {
  __syncthreads();
  if (threadIdx.x == 0) {
    asm volatile("s_waitcnt vmcnt(0)" ::: "memory");
    as_(&CTL[blockIdx.x * 32], ph);
  }
  if (threadIdx.x < 64) {
    for (;;) {
      bool ok = true;
      for (int b = (int)threadIdx.x; b < nblk; b += 64)
        ok &= (al(&CTL[b * 32]) >= ph);
      if (__all(ok)) break;
      __builtin_amdgcn_s_sleep(1);
    }
    asm volatile("" ::: "memory");
  }
  __syncthreads();
}

// ======================= FAT: single merged cooperative kernel =======================
__global__ __launch_bounds__(TPB) void cluster_fat(const float* __restrict__ pred,
                                                   int* __restrict__ out,
                                                   char* __restrict__ ws) {
  uint64_t* MASKW = (uint64_t*)(ws + F_MASK);
  uint32_t* WOFF = (uint32_t*)(ws + F_WOFF);
  uint64_t* UNCLC = (uint64_t*)(ws + F_UNCL);
  uint64_t* P1C = (uint64_t*)(ws + F_P1C);
  uint64_t* PK = (uint64_t*)(ws + F_PK);
  int* CTL = (int*)(ws + F_CTL);
  float2* CEXY = (float2*)(ws + F_CEXY);
  float* CSM = (float*)(ws + F_CSM);
  float* CSV = (float*)(ws + F_CSV);
  float* CSX = (float*)(ws + F_CSX);
  float* CSY = (float*)(ws + F_CSY);

  const int tid = threadIdx.x;
  const int lane = tid & 63;
  const int wid = tid >> 6;
  const int bid = blockIdx.x;
  const int nw = NBLK * (TPB / 64);          // loop-mapping wave count
  const int gw0 = bid * (TPB / 64) + wid;    // loop mapping (strided)

  __shared__ uint64_t lK[TPB / 64], lA[TPB / 64], lB[TPB / 64];
  __shared__ int scn[2][NBLK];
  __shared__ int lbin[256];
  __shared__ float s_cx[MAXI], s_cy[MAXI], s_sx[MAXI], s_sy[MAXI];
  __shared__ int s_sz[MAXI];

  int ph = 0;

  // ---- P1: mask words + per-block popcount sum (contiguous map, wave-private) ----
  {
    uint32_t wsum = 0;
    for (int k = 0; k < WPB / 4; k++) {
      int w = bid * WPB + wid * (WPB / 4) + k;
      int i = (w << 6) | lane;
      float smv = compute_sm(pred, i);
      uint64_t bal = __ballot(smv > 0.5f);
      if (lane == 0) MASKW[w] = bal;
      wsum += (uint32_t)__popcll(bal);
    }
    if (lane == 0) lA[wid] = wsum;
    __syncthreads();
    if (tid == 0) {
      uint32_t t = 0;
#pragma unroll
      for (int w2 = 0; w2 < TPB / 64; w2++) t += (uint32_t)lA[w2];
      as_(&CTL[FC_CSUM + bid], (int)t);
    }
    __syncthreads();
  }
  gbar_d(CTL, NBLK, ++ph);

  // ---- P2: redundant chunk scan, per-word offsets, compacted scatter, uncl init ----
  int cnt;
  {
    scn[0][tid] = al(&CTL[FC_CSUM + tid]);
    scn[0][tid + 256] = al(&CTL[FC_CSUM + tid + 256]);
    __syncthreads();
    int pp = 0;
    for (int off = 1; off < NBLK; off <<= 1) {
      int a0 = scn[pp][tid] + ((tid >= off) ? scn[pp][tid - off] : 0);
      int i1 = tid + 256;
      int a1 = scn[pp][i1] + ((i1 >= off) ? scn[pp][i1 - off] : 0);
      scn[pp ^ 1][tid] = a0;
      scn[pp ^ 1][i1] = a1;
      __syncthreads();
      pp ^= 1;
    }
    cnt = scn[pp][NBLK - 1];
    int cbase = (bid == 0) ? 0 : scn[pp][bid - 1];
    if (cnt > CMAX) cnt = CMAX;
    // per-word exclusive offsets within this block's 64 words (wave-0 shfl scan)
    if (tid < 64) {
      int w = bid * WPB + tid;
      int pc = (int)__popcll(MASKW[w]);
      int inc = pc;
#pragma unroll
      for (int off = 1; off < 64; off <<= 1) {
        int v = __shfl_up(inc, off, 64);
        if (tid >= off) inc += v;
      }
      WOFF[w] = (uint32_t)(cbase + inc - pc);
    }
    __syncthreads();
    // scatter compacted per-pixel data (agent atomics: cross-block consumers)
    for (int k = 0; k < WPB / 4; k++) {
      int w = bid * WPB + wid * (WPB / 4) + k;
      uint64_t mw = MASKW[w];
      if ((mw >> lane) & 1ull) {
        int i = (w << 6) | lane;
        int j = (int)WOFF[w] + (int)__popcll(mw & ((1ull << lane) - 1ull));
        if (j < CMAX) {
          float ex, ey; compute_emb(pred, i, ex, ey);
          uint64_t pe = ((uint64_t)(uint32_t)__float_as_int(ey) << 32) |
                        (uint32_t)__float_as_int(ex);
          as64((uint64_t*)&CEXY[j], pe);
          as_((int*)&CSM[j], __float_as_int(compute_sm(pred, i)));
          as_((int*)&CSV[j], __float_as_int(1.0f / (1.0f + expf(-pred[(size_t)4 * NPIX + i]))));
          as_((int*)&CSX[j], __float_as_int(expf(pred[(size_t)2 * NPIX + i] * 10.0f)));
          as_((int*)&CSY[j], __float_as_int(expf(pred[(size_t)3 * NPIX + i] * 10.0f)));
        }
      }
    }
    // uncl init on the LOOP mapping (wave-private with the loop's reads/writes)
    int cnw0 = (cnt + 63) >> 6;
    for (int w = gw0; w < cnw0; w += nw) {
      int rem = cnt - (w << 6);
      UNCLC[w] = (rem >= 64) ? ~0ull : ((1ull << rem) - 1ull);
    }
  }
  gbar_d(CTL, NBLK, ++ph);

  const int cnw = (cnt + 63) >> 6;

  // ---- pass A0: argmax(CSM); Sall = cnt ----
  {
    int par = (ph + 1) & 1;
    uint64_t key = 0, sa = 0, sb = 0;
    for (int w = gw0; w < cnw; w += nw) {
      int j = (w << 6) | lane;
      if (j < cnt) {
        float v = CSM[j];
        uint64_t k2 = ((uint64_t)(uint32_t)__float_as_int(v) << 32) | (uint32_t)~(uint32_t)j;
        if (k2 > key) key = k2;
      }
    }
    bred(key, sa, sb, lK, lA, lB);
    if (tid == 0) {
      uint64_t* s = &PK[((size_t)par * NBLK + bid) * 4];
      as64(s + 0, key); as64(s + 1, sa); as64(s + 2, sb);
    }
  }
  gbar_d(CTL, NBLK, ++ph);
  float val1; int seed1; int Sall = cnt;
  {
    uint64_t key, sa, sb;
    gred_pk(PK, ph & 1, NBLK, key, sa, sb, lK, lA, lB);
    val1 = __int_as_float((int)(key >> 32));
    seed1 = (int)~(uint32_t)key;
  }
  float cx1, cy1, sx1, sy1;
  {
    int j = (seed1 >= 0 && seed1 < cnt) ? seed1 : 0;
    float2 e = CEXY[j]; cx1 = e.x; cy1 = e.y; sx1 = CSX[j]; sy1 = CSY[j];
  }

  int count = 1, it = 0;
  while (Sall > 160 && count < 200 && it < 2000) {
    if (val1 < 0.5f) break;

    // ---- pass B: prop1 bits, cnt1, seed2 = argmax(CSV | prop1) ----
    {
      int par = (ph + 1) & 1;
      uint64_t key = 0, sa = 0, sb = 0;
      for (int w0 = gw0; w0 < cnw; w0 += nw * UNROLL) {
#pragma unroll
        for (int u = 0; u < UNROLL; u++) {
          int w = w0 + u * nw;
          if (w >= cnw) continue;
          int j = (w << 6) | lane;
          float z = 1e30f;
          if (j < cnt) {
            float2 e = CEXY[j];
            z = prop_z(e.x, e.y, cx1, cy1, sx1, sy1);
          }
          bool band = (z > BAND_LO) & (z < BAND_HI);
          bool p;
          if (__any(band)) p = (j < cnt) && (expf(-z) > 0.5f);
          else p = z < LN2_CMP;
          uint64_t r = __ballot(p);
          if (lane == 0) P1C[w] = r;   // plain: wave-private
          if (p) {
            sa++;
            float v = CSV[j];
            uint64_t k2 = ((uint64_t)(uint32_t)__float_as_int(v) << 32) | (uint32_t)~(uint32_t)j;
            if (k2 > key) key = k2;
          }
        }
      }
      bred(key, sa, sb, lK, lA, lB);
      if (tid == 0) {
        uint64_t* s = &PK[((size_t)par * NBLK + bid) * 4];
        as64(s + 0, key); as64(s + 1, sa); as64(s + 2, sb);
      }
    }
    gbar_d(CTL, NBLK, ++ph);
    int seed2, cnt1;
    {
      uint64_t key, sa, sb;
      gred_pk(PK, ph & 1, NBLK, key, sa, sb, lK, lA, lB);
      seed2 = (int)~(uint32_t)key;
      cnt1 = (int)sa;
    }
    bool big1 = cnt1 > 160;
    float cx2, cy2, sx2, sy2;
    {
      int j = (seed2 >= 0 && seed2 < cnt) ? seed2 : 0;
      float2 e = CEXY[j]; cx2 = e.x; cy2 = e.y; sx2 = CSX[j]; sy2 = CSY[j];
    }

    // ---- pass C (fused): prop2 counts/overlap + flags + uncl update + next argmax ----
    {
      int par = (ph + 1) & 1;
      uint64_t key = 0, sa = 0, sb = 0;
      for (int w0 = gw0; w0 < cnw; w0 += nw * UNROLL) {
#pragma unroll
        for (int u = 0; u < UNROLL; u++) {
          int w = w0 + u * nw;
          if (w >= cnw) continue;
          uint64_t uw = UNCLC[w];                  // plain: wave-private
          uint64_t p1w = big1 ? 0ull : P1C[w];
          int j = (w << 6) | lane;
          float z = 1e30f;
          if (j < cnt) {
            float2 e = CEXY[j];
            z = prop_z(e.x, e.y, cx2, cy2, sx2, sy2);
          }
          bool band = (z > BAND_LO) & (z < BAND_HI);
          bool p;
          if (__any(band)) p = (j < cnt) && (expf(-z) > 0.5f);
          else p = z < LN2_CMP;
          bool ub = ((uw >> lane) & 1ull) != 0;
          if (p) sa += ub ? 0x100000001ull : 1ull;   // c2 | ov<<32
          if (j == seed1) as_(&CTL[FC_FLG1], p ? 1 : 0);
          if (j == seed2) as_(&CTL[FC_FLG2], (p && ub) ? 1 : 0);
          bool fp = big1 ? p : (((p1w >> lane) & 1ull) != 0);
          bool nu = ub && !(fp || j == seed1 || (big1 && j == seed2));
          uint64_t r = __ballot(nu);
          if (lane == 0 && uw) UNCLC[w] = r;       // plain: wave-private
          if (nu) {
            sb++;
            float v = CSM[j];
            uint64_t k2 = ((uint64_t)(uint32_t)__float_as_int(v) << 32) | (uint32_t)~(uint32_t)j;
            if (k2 > key) key = k2;
          }
        }
      }
      bred(key, sa, sb, lK, lA, lB);
      if (tid == 0) {
        uint64_t* s = &PK[((size_t)par * NBLK + bid) * 4];
        as64(s + 0, key); as64(s + 1, sa); as64(s + 2, sb);
      }
    }
    gbar_d(CTL, NBLK, ++ph);
    {
      uint64_t key, sa, sb;
      gred_pk(PK, ph & 1, NBLK, key, sa, sb, lK, lA, lB);
      int cnt2 = (int)(uint32_t)sa;
      int ovl = (int)(uint32_t)(sa >> 32);
      ovl -= al(&CTL[FC_FLG1]);
      if (big1 && seed2 != seed1) ovl -= al(&CTL[FC_FLG2]);
      bool big2 = cnt2 > 160;
      int den = cnt2 > 1 ? cnt2 : 1;
      float ratio = (float)ovl / (float)den;
      bool accept = big1 && big2 && (ratio > 0.5f);
      if (accept) {
        if (tid == 0) {
          s_cx[count] = cx2; s_cy[count] = cy2;
          s_sx[count] = sx2; s_sy[count] = sy2;
          s_sz[count] = cnt2;
        }
        count++;
      }
      it++;
      val1 = __int_as_float((int)(key >> 32));
      seed1 = (int)~(uint32_t)key;
      Sall = (int)sb;
    }
    {
      int j = (seed1 >= 0 && seed1 < cnt) ? seed1 : 0;
      float2 e = CEXY[j]; cx1 = e.x; cy1 = e.y; sx1 = CSX[j]; sy1 = CSY[j];
    }
  }

  // ---- reconstruction (pixel space, contiguous map): out + zero-fill + bincount ----
  lbin[tid] = 0;
  __syncthreads();   // publishes tid0's s_* log writes block-wide
  for (int k = 0; k < WPB / 4; k++) {
    int w = bid * WPB + wid * (WPB / 4) + k;
    uint64_t mw = MASKW[w];
    int i = (w << 6) | lane;
    int id = 0;
    if ((mw >> lane) & 1ull) {
      int j = (int)WOFF[w] + (int)__popcll(mw & ((1ull << lane) - 1ull));
      if (j < CMAX) {
        float2 e = CEXY[j];
        for (int kk = 1; kk < count; kk++) {
          float z = prop_z(e.x, e.y, s_cx[kk], s_cy[kk], s_sx[kk], s_sy[kk]);
          bool band = (z > BAND_LO) & (z < BAND_HI);
          bool p;
          if (__any(band)) p = expf(-z) > 0.5f;
          else p = z < LN2_CMP;
          if (p) id = kk;
        }
      }
      atomicAdd(&lbin[id], 1);
    }
    out[i] = id;   // full-word coalesced store (zero-fill fused)
  }
  __syncthreads();
  if (lbin[tid] > 0)
    __hip_atomic_fetch_add(&CTL[FC_NOW + tid], lbin[tid], __ATOMIC_RELAXED,
                           __HIP_MEMORY_SCOPE_AGENT);
  gbar_d(CTL, NBLK, ++ph);
  lbin[tid] = al(&CTL[FC_NOW + tid]);
  __syncthreads();
  for (int k = 0; k < WPB / 4; k++) {
    int w = bid * WPB + wid * (WPB / 4) + k;
    for (int rep = 0; rep < 1; rep++) {
      int i = (w << 6) | lane;
      int id = out[i];   // plain: same wave wrote it
      if (id > 0) {
        int n = lbin[id];
        int sz = s_sz[id];
        bool rm = (n != sz) && ((n < 480) || ((float)n < 0.5f * (float)sz));
        if (rm) out[i] = 0;
      }
    }
  }
}

// ======================= THIN fallback (round-6, proven) =======================
__device__ __forceinline__ void gred(const uint64_t* PVp, const uint64_t* PAp,
                                     const uint64_t* PBp, int nblk,
                                     uint64_t& key, uint64_t& sa, uint64_t& sb,
                                     uint64_t* lK, uint64_t* lA, uint64_t* lB) {
  key = 0; sa = 0; sb = 0;
  for (int b = threadIdx.x; b < nblk; b += TPB) {
    uint64_t k2 = al64(&PVp[b]); if (k2 > key) key = k2;
    sa += al64(&PAp[b]);
    sb += al64(&PBp[b]);
  }
  bred(key, sa, sb, lK, lA, lB);
}

__device__ __forceinline__ void gbar_rel(int* CTL, int nblk, int ph) {
  __syncthreads();
  if (threadIdx.x == 0) {
    asm volatile("s_waitcnt vmcnt(0)" ::: "memory");
    as_(&CTL[blockIdx.x * 32], ph);
  }
  if (blockIdx.x == 0) {
    if (threadIdx.x < 64) {
      for (;;) {
        bool ok = true;
        for (int b = (int)threadIdx.x; b < nblk; b += 64)
          ok &= (al(&CTL[b * 32]) >= ph);
        if (__all(ok)) break;
        __builtin_amdgcn_s_sleep(1);
      }
      asm volatile("" ::: "memory");
      if (threadIdx.x == 0) as_(&CTL[TC_REL], ph);
    }
  } else {
    if (threadIdx.x == 0) {
      while (al(&CTL[TC_REL]) < ph) __builtin_amdgcn_s_sleep(1);
      asm volatile("" ::: "memory");
    }
  }
  __syncthreads();
}

__global__ void precompute_thin(const float* __restrict__ pred, int* __restrict__ out,
                                char* __restrict__ ws) {
  uint64_t* MASKW = (uint64_t*)(ws + T_MASK);
  uint64_t* UNCLW = (uint64_t*)(ws + T_UNCL);
  int* CTL = (int*)(ws + T_CTL);
  int gid = blockIdx.x * blockDim.x + threadIdx.x;
  int stride = gridDim.x * blockDim.x;
  for (int i = gid; i < NPIX; i += stride) {
    float smv = compute_sm(pred, i);
    unsigned long long bal = __ballot(smv > 0.5f);
    if ((threadIdx.x & 63) == 0) { MASKW[i >> 6] = bal; UNCLW[i >> 6] = bal; }
    out[i] = 0;
  }
  if (gid < TC_ZEND) CTL[gid] = 0;
}

__global__ __launch_bounds__(TPB) void cluster_thin(const float* __restrict__ pred,
                                                    int* __restrict__ out,
                                                    char* __restrict__ ws, int nblk) {
  uint64_t* MASKW = (uint64_t*)(ws + T_MASK);
  uint64_t* UNCLW = (uint64_t*)(ws + T_UNCL);
  uint64_t* P1W = (uint64_t*)(ws + T_P1);
  uint64_t* PV = (uint64_t*)(ws + T_PV);
  uint64_t* PSA = (uint64_t*)(ws + T_PSA);
  uint64_t* PSB = (uint64_t*)(ws + T_PSB);
  int* CTL = (int*)(ws + T_CTL);

  const int tid = threadIdx.x;
  const int lane = tid & 63;
  const int bid = blockIdx.x;
  const int nw = nblk * (TPB / 64);
  const int gw0 = bid * (TPB / 64) + (tid >> 6);

  __shared__ uint64_t lK[TPB / 64], lA[TPB / 64], lB[TPB / 64];
  __shared__ int lbin[256];
  __shared__ float s_cx[MAXI], s_cy[MAXI], s_sx[MAXI], s_sy[MAXI];
  __shared__ int s_sz[MAXI];

  int ph = 0;
  {
    int par = (ph + 1) & 1;
    uint64_t key = 0, sa = 0, sb = 0;
    for (int w = gw0; w < NWORD; w += nw) {
      uint64_t uw = UNCLW[w];
      if (!uw) continue;
      int i = (w << 6) | lane;
      if ((uw >> lane) & 1ull) {
        sa++;
        float v = compute_sm(pred, i);
        uint64_t k2 = ((uint64_t)(uint32_t)__float_as_int(v) << 32) | (uint32_t)~(uint32_t)i;
        if (k2 > key) key = k2;
      }
    }
    bred(key, sa, sb, lK, lA, lB);
    if (tid == 0) {
      as64(&PV[par * T_NBLK + bid], key);
      as64(&PSA[par * T_NBLK + bid], sa);
      as64(&PSB[par * T_NBLK + bid], sb);
    }
  }
  gbar_rel(CTL, nblk, ++ph);
  float val1; int seed1; int Sall;
  {
    int par = ph & 1;
    uint64_t key, sa, sb;
    gred(PV + par * T_NBLK, PSA + par * T_NBLK, PSB + par * T_NBLK, nblk, key, sa, sb, lK, lA, lB);
    val1 = __int_as_float((int)(key >> 32));
    seed1 = (int)~(uint32_t)key;
    Sall = (int)sa;
  }
  float cx1, cy1, sx1, sy1;
  {
    int bj = (seed1 >= 0 && seed1 < NPIX) ? seed1 : 0;
    compute_emb(pred, bj, cx1, cy1);
    sx1 = expf(pred[(size_t)2 * NPIX + bj] * 10.0f);
    sy1 = expf(pred[(size_t)3 * NPIX + bj] * 10.0f);
  }

  int count = 1, it = 0;
  while (Sall > 160 && count < 200 && it < 2000) {
    if (val1 < 0.5f) break;
    {
      int par = (ph + 1) & 1;
      uint64_t key = 0, sa = 0, sb = 0;
      for (int w = gw0; w < NWORD; w += nw) {
        uint64_t mw = MASKW[w];
        if (!mw) continue;
        int i = (w << 6) | lane;
        bool p = false;
        if ((mw >> lane) & 1ull) {
          float ex, ey; compute_emb(pred, i, ex, ey);
          p = prop_test(ex, ey, cx1, cy1, sx1, sy1);
        }
        uint64_t r = __ballot(p);
        if (lane == 0) P1W[w] = r;
        if (p) {
          sa++;
          float v = 1.0f / (1.0f + expf(-pred[(size_t)4 * NPIX + i]));
          uint64_t k2 = ((uint64_t)(uint32_t)__float_as_int(v) << 32) | (uint32_t)~(uint32_t)i;
          if (k2 > key) key = k2;
        }
      }
      bred(key, sa, sb, lK, lA, lB);
      if (tid == 0) {
        as64(&PV[par * T_NBLK + bid], key);
        as64(&PSA[par * T_NBLK + bid], sa);
        as64(&PSB[par * T_NBLK + bid], sb);
      }
    }
    gbar_rel(CTL, nblk, ++ph);
    int seed2, cnt1;
    {
      int par = ph & 1;
      uint64_t key, sa, sb;
      gred(PV + par * T_NBLK, PSA + par * T_NBLK, PSB + par * T_NBLK, nblk, key, sa, sb, lK, lA, lB);
      seed2 = (int)~(uint32_t)key;
      cnt1 = (int)sa;
    }
    bool big1 = cnt1 > 160;
    float cx2, cy2, sx2, sy2;
    {
      int bj = (seed2 >= 0 && seed2 < NPIX) ? seed2 : 0;
      compute_emb(pred, bj, cx2, cy2);
      sx2 = expf(pred[(size_t)2 * NPIX + bj] * 10.0f);
      sy2 = expf(pred[(size_t)3 * NPIX + bj] * 10.0f);
    }
    {
      int par = (ph + 1) & 1;
      uint64_t key = 0, sa = 0, sb = 0;
      for (int w = gw0; w < NWORD; w += nw) {
        uint64_t mw = MASKW[w];
        if (!mw) continue;
        uint64_t uw = UNCLW[w];
        uint64_t p1w = big1 ? 0ull : P1W[w];
        int i = (w << 6) | lane;
        bool p = false;
        if ((mw >> lane) & 1ull) {
          float ex, ey; compute_emb(pred, i, ex, ey);
          p = prop_test(ex, ey, cx2, cy2, sx2, sy2);
        }
        bool ub = ((uw >> lane) & 1ull) != 0;
        if (p) sa += ub ? 0x100000001ull : 1ull;
        if (i == seed1) as_(&CTL[TC_FLG1], p ? 1 : 0);
        if (i == seed2) as_(&CTL[TC_FLG2], (p && ub) ? 1 : 0);
        bool fp = big1 ? p : (((p1w >> lane) & 1ull) != 0);
        bool nu = ub && !(fp || i == seed1 || (big1 && i == seed2));
        uint64_t r = __ballot(nu);
        if (lane == 0 && uw) UNCLW[w] = r;
        if (nu) {
          sb++;
          float v = compute_sm(pred, i);
          uint64_t k2 = ((uint64_t)(uint32_t)__float_as_int(v) << 32) | (uint32_t)~(uint32_t)i;
          if (k2 > key) key = k2;
        }
      }
      bred(key, sa, sb, lK, lA, lB);
      if (tid == 0) {
        as64(&PV[par * T_NBLK + bid], key);
        as64(&PSA[par * T_NBLK + bid], sa);
        as64(&PSB[par * T_NBLK + bid], sb);
      }
    }
    gbar_rel(CTL, nblk, ++ph);
    {
      int par = ph & 1;
      uint64_t key, sa, sb;
      gred(PV + par * T_NBLK, PSA + par * T_NBLK, PSB + par * T_NBLK, nblk, key, sa, sb, lK, lA, lB);
      int cnt2 = (int)(uint32_t)sa;
      int ovl = (int)(uint32_t)(sa >> 32);
      ovl -= al(&CTL[TC_FLG1]);
      if (big1 && seed2 != seed1) ovl -= al(&CTL[TC_FLG2]);
      bool big2 = cnt2 > 160;
      int den = cnt2 > 1 ? cnt2 : 1;
      float ratio = (float)ovl / (float)den;
      bool accept = big1 && big2 && (ratio > 0.5f);
      if (accept) {
        if (tid == 0) {
          s_cx[count] = cx2; s_cy[count] = cy2;
          s_sx[count] = sx2; s_sy[count] = sy2;
          s_sz[count] = cnt2;
        }
        count++;
      }
      it++;
      val1 = __int_as_float((int)(key >> 32));
      seed1 = (int)~(uint32_t)key;
      Sall = (int)sb;
    }
    {
      int bj = (seed1 >= 0 && seed1 < NPIX) ? seed1 : 0;
      compute_emb(pred, bj, cx1, cy1);
      sx1 = expf(pred[(size_t)2 * NPIX + bj] * 10.0f);
      sy1 = expf(pred[(size_t)3 * NPIX + bj] * 10.0f);
    }
  }

  lbin[tid] = 0;
  __syncthreads();
  for (int w = gw0; w < NWORD; w += nw) {
    uint64_t mw = MASKW[w];
    int i = (w << 6) | lane;
    int id = 0;
    if ((mw >> lane) & 1ull) {
      float ex, ey; compute_emb(pred, i, ex, ey);
      for (int k = 1; k < count; k++)
        if (prop_test(ex, ey, s_cx[k], s_cy[k], s_sx[k], s_sy[k])) id = k;
    }
    out[i] = id;
    atomicAdd(&lbin[id], 1);
  }
  __syncthreads();
  if (lbin[tid] > 0)
    __hip_atomic_fetch_add(&CTL[TC_NOW + tid], lbin[tid], __ATOMIC_RELAXED,
                           __HIP_MEMORY_SCOPE_AGENT);
  gbar_rel(CTL, nblk, ++ph);
  lbin[tid] = al(&CTL[TC_NOW + tid]);
  __syncthreads();
  for (int w = gw0; w < NWORD; w += nw) {
    int i = (w << 6) | lane;
    int id = out[i];
    if (id > 0) {
      int n = lbin[id];
      int sz = s_sz[id];
      bool rm = (n != sz) && ((n < 480) || ((float)n < 0.5f * (float)sz));
      if (rm) out[i] = 0;
    }
  }
}

static void launch_thin(const float* pred, int* out, char* ws, int numCU,
                        hipStream_t stream) {
  hipLaunchKernelGGL(precompute_thin, dim3(4096), dim3(TPB), 0, stream, pred, out, ws);
  int nblk = T_NBLK;
  int maxPerCU = 0;
  if (hipOccupancyMaxActiveBlocksPerMultiprocessor(&maxPerCU, (const void*)cluster_thin,
                                                   TPB, 0) == hipSuccess && maxPerCU > 0) {
    long long cap = (long long)maxPerCU * numCU;
    if (cap < nblk) nblk = (int)cap;
  }
  if (nblk < 1) nblk = 1;
  void* args[] = {(void*)&pred, (void*)&out, (void*)&ws, (void*)&nblk};
  hipLaunchCooperativeKernel((void*)cluster_thin, dim3(nblk), dim3(TPB), args, 0, stream);
}

extern "C" void kernel_launch(void* const* d_in, const int* in_sizes, int n_in,
                              void* d_out, int out_size, void* d_ws, size_t ws_size,
                              hipStream_t stream) {
  const float* pred = (const float*)d_in[0];
  int* out = (int*)d_out;
  char* ws = (char*)d_ws;

  int dev = 0;
  hipGetDevice(&dev);
  int numCU = 0;
  hipDeviceGetAttribute(&numCU, hipDeviceAttributeMultiprocessorCount, dev);
  if (numCU <= 0) numCU = 256;

  bool fat_ok = false;
  if (ws_size >= FAT_NEED) {
    int maxPerCU = 0;
    if (hipOccupancyMaxActiveBlocksPerMultiprocessor(&maxPerCU, (const void*)cluster_fat,
                                                     TPB, 0) == hipSuccess &&
        (long long)maxPerCU * numCU >= NBLK)
      fat_ok = true;
  }

  if (fat_ok) {
    hipMemsetAsync(ws + F_CTL, 0, FC_MEMSET_BYTES, stream);
    void* args[] = {(void*)&pred, (void*)&out, (void*)&ws};
    hipLaunchCooperativeKernel((void*)cluster_fat, dim3(NBLK), dim3(TPB), args, 0, stream);
  } else {
    launch_thin(pred, out, ws, numCU, stream);
  }
}